// Round 1
// 198.722 us; speedup vs baseline: 1.0365x; 1.0365x over previous
//
#include <hip/hip_runtime.h>
#include <stdint.h>

// Problem constants (fixed by the reference)
#define H 56
#define W 56
#define HW (H * W)          // 3136
#define CIN 256
#define IMG (CIN * HW)      // 802816 elements per image
#define EPS 1e-5f

#define ROWW 8              // u32 words per tile row: 32B = 64 nibbles
#define TROWS 58            // 56 image rows + top/bottom padding rows
#define TILE_SZ (TROWS * ROWW)

// Strict fp32 RN ops, immune to -ffp-contract (inline asm cannot be fused).
// The np reference's exact-zero BN outputs (sign->0) only reproduce with the
// two-rounding chain round(round(x*inv)+bias).
__device__ __forceinline__ float mul_rn(float a, float b) {
    float d; asm("v_mul_f32 %0, %1, %2" : "=v"(d) : "v"(a), "v"(b)); return d;
}
__device__ __forceinline__ float add_rn(float a, float b) {
    float d; asm("v_add_f32 %0, %1, %2" : "=v"(d) : "v"(a), "v"(b)); return d;
}
__device__ __forceinline__ float sub_rn(float a, float b) {
    float d; asm("v_sub_f32 %0, %1, %2" : "=v"(d) : "v"(a), "v"(b)); return d;
}

// ---------------------------------------------------------------------------
// Fused: BN -> ternary sign -> XNOR-popcount grouped 3x3 conv -> shuffle -> +x
// One block per (n, g) PAIR of planes {n0, n0+nHalf} (same g => same BN consts
// and weights). 256 threads. The second plane's global loads are issued into
// registers right after the tile-0 barrier and their latency is hidden under
// Phase B of plane 0 (software pipeline; LDS tiles are double-buffered).
//
// LDS layout per plane: 58 rows x 8 u32; row r+1 holds image row r as packed
// 4-bit nibbles (nibble w = 4 channel bits of pixel w). Rows 0/57 and nibble
// columns 56..63 stay zero => z-plane zeros subsume all geometric padding.
// ---------------------------------------------------------------------------

// Issue the 12 float4 loads (3 tasks/thread, tasks tid, tid+256, tid+512).
__device__ __forceinline__ void stage_issue(const float* __restrict__ Xn, int g, int tid,
                                            float4 v[3][4]) {
#pragma unroll
    for (int i = 0; i < 3; ++i) {
        int t   = tid + i * 256;
        int r   = t / 14;
        int cg  = t - r * 14;
        int off = r * W + cg * 4;
#pragma unroll
        for (int ci = 0; ci < 4; ++ci)
            v[i][ci] = *reinterpret_cast<const float4*>(Xn + (size_t)(g * 4 + ci) * HW + off);
    }
}

// BN + ternary-sign pack of 4 channels x 4 px into (s16, z16).
__device__ __forceinline__ void bn_pack(const float4 q[4], const float inv[4], const float bias[4],
                                        uint32_t& s16, uint32_t& z16) {
    s16 = 0u; z16 = 0u;
#pragma unroll
    for (int ci = 0; ci < 4; ++ci) {
        float t0 = add_rn(mul_rn(q[ci].x, inv[ci]), bias[ci]);
        float t1 = add_rn(mul_rn(q[ci].y, inv[ci]), bias[ci]);
        float t2 = add_rn(mul_rn(q[ci].z, inv[ci]), bias[ci]);
        float t3 = add_rn(mul_rn(q[ci].w, inv[ci]), bias[ci]);
        s16 |= ((t0 > 0.f ? 1u : 0u) << ci)        | ((t1 > 0.f ? 1u : 0u) << (4 + ci))
             | ((t2 > 0.f ? 1u : 0u) << (8 + ci))  | ((t3 > 0.f ? 1u : 0u) << (12 + ci));
        z16 |= ((t0 != 0.f ? 1u : 0u) << ci)       | ((t1 != 0.f ? 1u : 0u) << (4 + ci))
             | ((t2 != 0.f ? 1u : 0u) << (8 + ci)) | ((t3 != 0.f ? 1u : 0u) << (12 + ci));
    }
}

// Convert staged registers into one LDS tile; threads 0..15 also handle the 16
// leftover tasks (768..783) with inline loads (kept out of registers so the
// staged footprint stays a uniform 48 VGPRs).
__device__ __forceinline__ void stage_convert(const float4 v[3][4], const float inv[4],
                                              const float bias[4],
                                              uint32_t* s_t, uint32_t* z_t,
                                              int tid, const float* __restrict__ Xn, int g) {
#pragma unroll
    for (int i = 0; i < 3; ++i) {
        int t  = tid + i * 256;
        int r  = t / 14;
        int cg = t - r * 14;
        uint32_t s16, z16;
        bn_pack(v[i], inv, bias, s16, z16);
        reinterpret_cast<uint16_t*>(&s_t[(r + 1) * ROWW])[cg] = (uint16_t)s16;
        reinterpret_cast<uint16_t*>(&z_t[(r + 1) * ROWW])[cg] = (uint16_t)z16;
    }
    if (tid < 16) {
        int t   = 768 + tid;
        int r   = t / 14;
        int cg  = t - r * 14;
        int off = r * W + cg * 4;
        float4 q[4];
#pragma unroll
        for (int ci = 0; ci < 4; ++ci)
            q[ci] = *reinterpret_cast<const float4*>(Xn + (size_t)(g * 4 + ci) * HW + off);
        uint32_t s16, z16;
        bn_pack(q, inv, bias, s16, z16);
        reinterpret_cast<uint16_t*>(&s_t[(r + 1) * ROWW])[cg] = (uint16_t)s16;
        reinterpret_cast<uint16_t*>(&z_t[(r + 1) * ROWW])[cg] = (uint16_t)z16;
    }
}

// Phase B: per task = (output row h, 4-px group), 6 two-dword LDS reads,
// XNOR-popcount for 4 filters x 4 px, shuffled float4 shortcut + store.
// Shortcut loads are issued at the top so their (L3) latency hides under the
// popcount math.
__device__ __forceinline__ void phaseB(const uint32_t* s_t, const uint32_t* z_t,
                                       const float* __restrict__ Xn, float* __restrict__ On,
                                       int g, int tid,
                                       const uint32_t wsj[4][3], const uint32_t wzj[4][3],
                                       bool full) {
    for (int task = tid; task < 56 * 14; task += 256) {
        int h  = task / 14;
        int cg = task - h * 14;
        int w0 = cg * 4;
        size_t pbase = (size_t)h * W + w0;

        float4 sc[4];
#pragma unroll
        for (int j = 0; j < 4; ++j)
            sc[j] = *reinterpret_cast<const float4*>(Xn + (size_t)(j * 64 + g) * HW + pbase);

        uint64_t vs[3], vz[3];
        int off;
        if (w0 == 0) {
            off = 0;
#pragma unroll
            for (int r = 0; r < 3; ++r) {
                int base = (h + r) * ROWW;
                vs[r] = (((uint64_t)s_t[base] | ((uint64_t)s_t[base + 1] << 32)) << 4);
                vz[r] = (((uint64_t)z_t[base] | ((uint64_t)z_t[base + 1] << 32)) << 4);
            }
        } else {
            int st = 4 * w0 - 4;
            int i0 = st >> 5;
            off = st & 31;
#pragma unroll
            for (int r = 0; r < 3; ++r) {
                int base = (h + r) * ROWW + i0;
                vs[r] = ((uint64_t)s_t[base] | ((uint64_t)s_t[base + 1] << 32));
                vz[r] = ((uint64_t)z_t[base] | ((uint64_t)z_t[base + 1] << 32));
            }
        }

        int res[4][4];
        if (full) {
#pragma unroll
            for (int k = 0; k < 4; ++k) {
                int sh = off + 4 * k;
                uint32_t s0 = (uint32_t)(vs[0] >> sh) & 0xFFFu;
                uint32_t s1 = (uint32_t)(vs[1] >> sh) & 0xFFFu;
                uint32_t s2 = (uint32_t)(vs[2] >> sh) & 0xFFFu;
                uint32_t z0 = (uint32_t)(vz[0] >> sh) & 0xFFFu;
                uint32_t z1 = (uint32_t)(vz[1] >> sh) & 0xFFFu;
                uint32_t z2 = (uint32_t)(vz[2] >> sh) & 0xFFFu;
                int vb = __popc(z0) + __popc(z1) + __popc(z2);
#pragma unroll
                for (int j = 0; j < 4; ++j) {
                    int pc = __popc((s0 ^ wsj[j][0]) & z0)
                           + __popc((s1 ^ wsj[j][1]) & z1)
                           + __popc((s2 ^ wsj[j][2]) & z2);
                    res[j][k] = vb - 2 * pc;
                }
            }
        } else {
#pragma unroll
            for (int k = 0; k < 4; ++k) {
                int sh = off + 4 * k;
                uint32_t s0 = (uint32_t)(vs[0] >> sh) & 0xFFFu;
                uint32_t s1 = (uint32_t)(vs[1] >> sh) & 0xFFFu;
                uint32_t s2 = (uint32_t)(vs[2] >> sh) & 0xFFFu;
                uint32_t z0 = (uint32_t)(vz[0] >> sh) & 0xFFFu;
                uint32_t z1 = (uint32_t)(vz[1] >> sh) & 0xFFFu;
                uint32_t z2 = (uint32_t)(vz[2] >> sh) & 0xFFFu;
#pragma unroll
                for (int j = 0; j < 4; ++j) {
                    uint32_t m0 = z0 & wzj[j][0];
                    uint32_t m1 = z1 & wzj[j][1];
                    uint32_t m2 = z2 & wzj[j][2];
                    int vb = __popc(m0) + __popc(m1) + __popc(m2);
                    int pc = __popc((s0 ^ wsj[j][0]) & m0)
                           + __popc((s1 ^ wsj[j][1]) & m1)
                           + __popc((s2 ^ wsj[j][2]) & m2);
                    res[j][k] = vb - 2 * pc;
                }
            }
        }

        // Epilogue: shuffled channel c' = j*64 + g; float4 shortcut + store.
#pragma unroll
        for (int j = 0; j < 4; ++j) {
            size_t cofs = (size_t)(j * 64 + g) * HW + pbase;
            float4 o;
            o.x = add_rn((float)res[j][0], sc[j].x);
            o.y = add_rn((float)res[j][1], sc[j].y);
            o.z = add_rn((float)res[j][2], sc[j].z);
            o.w = add_rn((float)res[j][3], sc[j].w);
            *reinterpret_cast<float4*>(On + cofs) = o;
        }
    }
}

__global__ __launch_bounds__(256, 4)
void binconv_kernel(const float* __restrict__ X,
                    const float* __restrict__ Wt,
                    const float* __restrict__ gamma,
                    const float* __restrict__ beta,
                    const float* __restrict__ mean,
                    const float* __restrict__ var,
                    float* __restrict__ out, int nHalf) {
    __shared__ uint32_t s_tile[2][TILE_SZ];   // sign nibbles, double-buffered
    __shared__ uint32_t z_tile[2][TILE_SZ];   // nonzero nibbles
    __shared__ uint32_t ws_l[4][3];           // weight sign rows (12-bit)
    __shared__ uint32_t wz_l[4][3];           // weight nz   rows (12-bit)

    const int bx  = blockIdx.x;
    const int n0  = bx >> 6;
    const int g   = bx & 63;
    const int tid = threadIdx.x;

    // Zero both tile buffers (interiors are overwritten after the barriers).
    for (int i = tid; i < 2 * TILE_SZ; i += 256) {
        (&s_tile[0][0])[i] = 0u;
        (&z_tile[0][0])[i] = 0u;
    }

    // Threads 0..3 pack this group's 4 filters into 12-bit row patterns.
    // bit = kw*4 + ci  (kw aligns with window nibble: w-1, w, w+1).
    if (tid < 4) {
        const float* wc = Wt + (size_t)(g * 4 + tid) * 36;   // [ci][kh][kw]
        for (int r = 0; r < 3; ++r) {
            uint32_t s = 0, z = 0;
            for (int ci = 0; ci < 4; ++ci)
                for (int kw = 0; kw < 3; ++kw) {
                    float v = wc[ci * 9 + r * 3 + kw];
                    int b = kw * 4 + ci;
                    s |= (v > 0.f  ? 1u : 0u) << b;
                    z |= (v != 0.f ? 1u : 0u) << b;
                }
            ws_l[tid][r] = s; wz_l[tid][r] = z;
        }
    }

    // BN constants (strict np fp32 chain).
    float inv[4], bias[4];
#pragma unroll
    for (int ci = 0; ci < 4; ++ci) {
        int c = g * 4 + ci;
        float s  = sqrtf(var[c] + EPS);   // correctly rounded
        float r  = 1.0f / s;              // correctly rounded
        float iv = mul_rn(gamma[c], r);
        inv[ci]  = iv;
        bias[ci] = sub_rn(beta[c], mul_rn(mean[c], iv));
    }

    const float* Xn0 = X   + (size_t)n0 * IMG;
    const float* Xn1 = X   + (size_t)(n0 + nHalf) * IMG;
    float*       On0 = out + (size_t)n0 * IMG;
    float*       On1 = out + (size_t)(n0 + nHalf) * IMG;

    // Plane-0 loads issued before the barrier: latency hides under the
    // zeroing / weight-pack / BN-const setup above (barrier drains them, but
    // they are needed immediately after anyway).
    float4 v0[3][4];
    stage_issue(Xn0, g, tid, v0);

    __syncthreads();                       // zero + packed weights visible

    stage_convert(v0, inv, bias, s_tile[0], z_tile[0], tid, Xn0, g);

    // Weight masks to SGPRs (block-uniform values; frees ~24 VGPRs and lets
    // the XOR/AND operands come from scalar regs).
    uint32_t wsj[4][3], wzj[4][3];
    bool full = true;
#pragma unroll
    for (int j = 0; j < 4; ++j)
#pragma unroll
        for (int r = 0; r < 3; ++r) {
            wsj[j][r] = __builtin_amdgcn_readfirstlane(ws_l[j][r]);
            wzj[j][r] = __builtin_amdgcn_readfirstlane(wz_l[j][r]);
            full = full && (wzj[j][r] == 0xFFFu);
        }

    __syncthreads();                       // tile 0 ready

    // Pipeline: issue plane-1 loads NOW (after the barrier, so the compiler's
    // pre-barrier vmcnt(0) cannot drain them), then compute plane 0. The
    // popcount phase hides the ~900-cycle HBM latency.
    float4 v1[3][4];
    stage_issue(Xn1, g, tid, v1);

    phaseB(s_tile[0], z_tile[0], Xn0, On0, g, tid, wsj, wzj, full);

    stage_convert(v1, inv, bias, s_tile[1], z_tile[1], tid, Xn1, g);

    __syncthreads();                       // tile 1 ready

    phaseB(s_tile[1], z_tile[1], Xn1, On1, g, tid, wsj, wzj, full);
}

// ---------------------------------------------------------------------------
extern "C" void kernel_launch(void* const* d_in, const int* in_sizes, int n_in,
                              void* d_out, int out_size, void* d_ws, size_t ws_size,
                              hipStream_t stream) {
    const float* X     = (const float*)d_in[0];
    const float* Wt    = (const float*)d_in[1];
    const float* gamma = (const float*)d_in[2];
    const float* beta  = (const float*)d_in[3];
    const float* mean  = (const float*)d_in[4];
    const float* var   = (const float*)d_in[5];
    float* out = (float*)d_out;

    int N     = in_sizes[0] / IMG;    // 32
    int nHalf = N >> 1;               // 16: block handles planes (n, g) and (n+16, g)

    binconv_kernel<<<nHalf * 64, 256, 0, stream>>>(X, Wt, gamma, beta, mean, var, out, nHalf);
}